// Round 13
// baseline (15704.561 us; speedup 1.0000x reference)
//
#include <hip/hip_runtime.h>
#include <math.h>

// B=256, T_ENC=200, D=256, T_MEL=1000, NMEL=80, R=5, IN_R=400, Td=200
#define ALIGN_OFF 20480000   // 256*200*400

typedef __fp16 h2_t __attribute__((ext_vector_type(2)));

__device__ __forceinline__ float sigf(float x) {
    return __builtin_amdgcn_rcpf(1.0f + __expf(-x));
}
__device__ __forceinline__ float tanhff(float x) {
    float e = __expf(2.0f * x);
    return 1.0f - 2.0f * __builtin_amdgcn_rcpf(e + 1.0f);
}
__device__ __forceinline__ unsigned short f2bf(float x) {
    unsigned u = __float_as_uint(x);
    return (unsigned short)((u + 0x7FFFu + ((u >> 16) & 1u)) >> 16);
}
__device__ __forceinline__ float blo(unsigned u) { return __uint_as_float(u << 16); }
__device__ __forceinline__ float bhi(unsigned u) { return __uint_as_float(u & 0xffff0000u); }
// pack two f32 -> f16x2 (RTZ)
__device__ __forceinline__ unsigned pkh(float a, float b) {
    h2_t r = __builtin_amdgcn_cvt_pkrtz(a, b);
    return __builtin_bit_cast(unsigned, r);
}
// f16 pair dot with f32 accumulate
__device__ __forceinline__ float dot2(unsigned w, unsigned a, float c) {
#if __has_builtin(__builtin_amdgcn_fdot2)
    return __builtin_amdgcn_fdot2(__builtin_bit_cast(h2_t, w),
                                  __builtin_bit_cast(h2_t, a), c, false);
#else
    h2_t wv = __builtin_bit_cast(h2_t, w), av = __builtin_bit_cast(h2_t, a);
    return c + (float)wv.x * (float)av.x + (float)wv.y * (float)av.y;
#endif
}
__device__ __forceinline__ float dot8(uint4 w, uint4 a, float c) {
    c = dot2(w.x, a.x, c); c = dot2(w.y, a.y, c);
    c = dot2(w.z, a.z, c); return dot2(w.w, a.w, c);
}

// ---------------------------------------------------------------------------
// 128x128-tile fp32 GEMM (prenet / processed_memory / mel).
// AMODE: 0 plain; 2 teacher-forcing virtual A (prenet1)
// EPI: 0 plain, 1 relu, 2 mel-layout store, 3 bf16 store (ld 256),
//      4 relu + f16 store (ld 128 halves = 64 uints)
// ---------------------------------------------------------------------------
template<int AMODE, int EPI>
__global__ __launch_bounds__(256)
void gemm128(const float* __restrict__ A, int lda,
             const float* __restrict__ W, int ldw,
             const float* __restrict__ bias,
             float* __restrict__ C, int ldc, int M, int N, int K)
{
    __shared__ float As[16][128];
    __shared__ float Bs[16][128];
    const int m0 = blockIdx.x * 128, n0 = blockIdx.y * 128;
    const int tid = threadIdx.x;
    const int tx = tid & 15, ty = tid >> 4;
    float acc[8][8] = {};
    for (int k0 = 0; k0 < K; k0 += 16) {
        {
            const int m = tid >> 1, h = (tid & 1) * 8;
            const int grow = m0 + m;
            float4 a0, a1;
            if (AMODE == 2) {
                int t = grow >> 8, b = grow & 255;
                if (t == 0) { a0 = make_float4(0, 0, 0, 0); a1 = a0; }
                else {
                    const float* p = A + (size_t)b * 80000 + (t - 1) * 400 + k0 + h;
                    a0 = *(const float4*)p; a1 = *(const float4*)(p + 4);
                }
            } else {
                const float* p = A + (size_t)grow * lda + k0 + h;
                a0 = *(const float4*)p; a1 = *(const float4*)(p + 4);
            }
            As[h + 0][m] = a0.x; As[h + 1][m] = a0.y; As[h + 2][m] = a0.z; As[h + 3][m] = a0.w;
            As[h + 4][m] = a1.x; As[h + 5][m] = a1.y; As[h + 6][m] = a1.z; As[h + 7][m] = a1.w;
            const int gn = n0 + m;
            float4 b0, b1;
            if (gn < N) {
                const float* p = W + (size_t)gn * ldw + k0 + h;
                b0 = *(const float4*)p; b1 = *(const float4*)(p + 4);
            } else { b0 = make_float4(0, 0, 0, 0); b1 = b0; }
            Bs[h + 0][m] = b0.x; Bs[h + 1][m] = b0.y; Bs[h + 2][m] = b0.z; Bs[h + 3][m] = b0.w;
            Bs[h + 4][m] = b1.x; Bs[h + 5][m] = b1.y; Bs[h + 6][m] = b1.z; Bs[h + 7][m] = b1.w;
        }
        __syncthreads();
        #pragma unroll
        for (int kk = 0; kk < 16; ++kk) {
            float av[8], bv[8];
            *(float4*)&av[0] = *(const float4*)&As[kk][ty * 8];
            *(float4*)&av[4] = *(const float4*)&As[kk][ty * 8 + 4];
            *(float4*)&bv[0] = *(const float4*)&Bs[kk][tx * 8];
            *(float4*)&bv[4] = *(const float4*)&Bs[kk][tx * 8 + 4];
            #pragma unroll
            for (int i = 0; i < 8; ++i)
                #pragma unroll
                for (int j = 0; j < 8; ++j)
                    acc[i][j] += av[i] * bv[j];
        }
        __syncthreads();
    }
    #pragma unroll
    for (int i = 0; i < 8; ++i) {
        const int row = m0 + ty * 8 + i;
        const int t_ = row >> 8, b_ = row & 255;
        #pragma unroll
        for (int j4 = 0; j4 < 2; ++j4) {
            const int col = n0 + tx * 8 + j4 * 4;
            if (col >= N) continue;
            float4 v;
            float* pv = &v.x;
            #pragma unroll
            for (int u = 0; u < 4; ++u) {
                float x = acc[i][j4 * 4 + u] + (bias ? bias[col + u] : 0.0f);
                if (EPI == 1 || EPI == 4) x = fmaxf(x, 0.0f);
                pv[u] = x;
            }
            if (EPI == 2)      *(float4*)(C + (size_t)b_ * 80000 + t_ * 400 + col) = v;
            else if (EPI == 3) {
                ushort4 o;
                o.x = f2bf(pv[0]); o.y = f2bf(pv[1]); o.z = f2bf(pv[2]); o.w = f2bf(pv[3]);
                *(ushort4*)((unsigned short*)C + (size_t)row * 256 + col) = o;
            } else if (EPI == 4) {
                uint2 o; o.x = pkh(pv[0], pv[1]); o.y = pkh(pv[2], pv[3]);
                *(uint2*)((unsigned*)C + (size_t)row * 64 + (col >> 1)) = o;
            } else *(float4*)(C + (size_t)row * ldc + col) = v;
        }
    }
}

// ---------------------------------------------------------------------------
// Pack W [N][K] f32 -> f16 [K/8][N] uint4 (8 halves per entry).
// ---------------------------------------------------------------------------
__global__ __launch_bounds__(256)
void pack_wh(const float* __restrict__ W, uint4* __restrict__ P, int N, int K)
{
    const int tot = N * (K >> 3);
    for (int i = blockIdx.x * 256 + threadIdx.x; i < tot; i += gridDim.x * 256) {
        const int n = i % N, k8 = i / N;
        const float* s = W + (size_t)n * K + (k8 << 3);
        uint4 o;
        o.x = pkh(s[0], s[1]); o.y = pkh(s[2], s[3]);
        o.z = pkh(s[4], s[5]); o.w = pkh(s[6], s[7]);
        P[(size_t)k8 * N + n] = o;
    }
}

// fp32 -> bf16 elementwise pack
__global__ __launch_bounds__(256)
void pack_bf16(const float* __restrict__ src, unsigned short* __restrict__ dst, int n)
{
    for (int i = (blockIdx.x * 256 + threadIdx.x) * 4; i < n; i += gridDim.x * 1024) {
        float4 v = *(const float4*)(src + i);
        ushort4 o;
        o.x = f2bf(v.x); o.y = f2bf(v.y); o.z = f2bf(v.z); o.w = f2bf(v.w);
        *(ushort4*)(dst + i) = o;
    }
}

// ---------------------------------------------------------------------------
// Zero-barrier persistent decoder: block b owns batch row b completely.
// pm row LDS-resident; enc streams from L2/L3; state in LDS; f16 weights,
// 768 threads = 768 gate cols (12 waves issuing in every dot phase).
// Round-13 tweaks: dual-accumulator dot loops (breaks the serial dot2 chain,
// 2x in-flight loads), X2 prefetch at P3 (off the P1 critical path),
// one-time score-tail fill.
// ---------------------------------------------------------------------------
__global__ __launch_bounds__(768)
void decoder_loop(
    const uint4* __restrict__ X2h4,          // [200*256][16] uint4, f16 prenet out
    const unsigned short* __restrict__ pmH,  // [256][200][256] bf16
    const unsigned short* __restrict__ encH, // [256][200][256] bf16
    const int*   __restrict__ mlen,
    const uint4* __restrict__ aWihH, const float* __restrict__ abih,
    const uint4* __restrict__ aWhhH, const float* __restrict__ abhh,
    const uint4* __restrict__ qWH,   const float* __restrict__ vW,
    const uint4* __restrict__ pjWH,  const float* __restrict__ pjb,
    const uint4* __restrict__ w1ihH, const float* __restrict__ w1bih,
    const uint4* __restrict__ w1hhH, const float* __restrict__ w1bhh,
    const uint4* __restrict__ w2ihH, const float* __restrict__ w2bih,
    const uint4* __restrict__ w2hhH, const float* __restrict__ w2bhh,
    float* __restrict__ dall, float* __restrict__ alout)
{
    __shared__ unsigned short pmS[51200];    // this row's pm, bf16 (100 KB)
    __shared__ uint4 xcat[48];               // f16 [x2_t (16) | att (32)]
    __shared__ unsigned ha_h[128], h1_h[128], h2_h[128], d0_h[128], d1_h[128];
    __shared__ float hA[256], h1s[256], h2s[256], d0s[256], d1s[256];
    __shared__ float qv[256], vvS[256];
    __shared__ float sc[200], al[208];
    __shared__ float gi[768], gh[768];
    __shared__ float part[12][256];

    const int b = blockIdx.x, tid = threadIdx.x;
    const int wv = tid >> 6, ln = tid & 63;

    // one-time init: pm row -> LDS, states zero, score-tail fill
    {
        const uint4* psrc = (const uint4*)(pmH + (size_t)b * 51200);
        for (int i = tid; i < 6400; i += 768) ((uint4*)pmS)[i] = psrc[i];
        if (tid < 256) { vvS[tid] = vW[tid]; hA[tid] = 0.f; h1s[tid] = 0.f; h2s[tid] = 0.f; }
        if (tid < 128) { ha_h[tid] = 0u; h1_h[tid] = 0u; h2_h[tid] = 0u; }
        if (tid < 32)  xcat[16 + tid] = make_uint4(0, 0, 0, 0);   // att = 0
        if (tid < 200) sc[tid] = -1e9f;                           // tail persists
        if (tid >= 704 && tid < 720) xcat[tid - 704] = X2h4[(size_t)b * 16 + (tid - 704)]; // t=0
    }
    const int len = mlen[b];
    const unsigned short* encG = encH + (size_t)b * 51200;
    __syncthreads();

    for (int t = 0; t < 200; ++t) {
        // ---- P1: attention GRU  h_a' = GRU([x2_t | att], h_a) ----
        // (xcat[0..15] was prefetched: init block for t=0, P3 of t-1 otherwise)
        {
            float ai0 = 0.f, ai1 = 0.f, ah0 = 0.f, ah1 = 0.f;
            const uint4* wp = aWihH + tid;
            #pragma unroll 8
            for (int k8 = 0; k8 < 48; k8 += 2) {
                ai0 = dot8(wp[(size_t)k8 * 768], xcat[k8], ai0);
                ai1 = dot8(wp[(size_t)(k8 + 1) * 768], xcat[k8 + 1], ai1);
            }
            const uint4* wq = aWhhH + tid;
            const uint4* hc = (const uint4*)ha_h;
            #pragma unroll 8
            for (int k8 = 0; k8 < 32; k8 += 2) {
                ah0 = dot8(wq[(size_t)k8 * 768], hc[k8], ah0);
                ah1 = dot8(wq[(size_t)(k8 + 1) * 768], hc[k8 + 1], ah1);
            }
            gi[tid] = ai0 + ai1 + abih[tid];
            gh[tid] = ah0 + ah1 + abhh[tid];
        }
        __syncthreads();
        if (tid < 256) {
            const float r = sigf(gi[tid] + gh[tid]);
            const float z = sigf(gi[256 + tid] + gh[256 + tid]);
            const float n = tanhff(gi[512 + tid] + r * gh[512 + tid]);
            const float hp = (1.f - z) * n + z * hA[tid];
            hA[tid] = hp;
            const float hq = __shfl_down(hp, 1);
            if (!(tid & 1)) ha_h[tid >> 1] = pkh(hp, hq);
        }
        __syncthreads();

        // ---- P2: q = h_a' @ qW^T ----
        if (tid < 256) {
            float s0 = 0.f, s1 = 0.f;
            const uint4* qp = qWH + tid;
            const uint4* hc = (const uint4*)ha_h;
            #pragma unroll 8
            for (int k8 = 0; k8 < 32; k8 += 2) {
                s0 = dot8(qp[(size_t)k8 * 256], hc[k8], s0);
                s1 = dot8(qp[(size_t)(k8 + 1) * 256], hc[k8 + 1], s1);
            }
            qv[tid] = s0 + s1;
        }
        __syncthreads();
        // ---- scores from LDS pm: sc[i] = v . tanh(pm[i] + q), i < len ----
        {
            const float4 q4 = ((const float4*)qv)[ln];
            const float4 v4 = ((const float4*)vvS)[ln];
            for (int i = wv; i < len; i += 12) {
                const uint2 pr = *(const uint2*)(pmS + i * 256 + ln * 4);
                float p = v4.x * tanhff(blo(pr.x) + q4.x)
                        + v4.y * tanhff(bhi(pr.x) + q4.y)
                        + v4.z * tanhff(blo(pr.y) + q4.z)
                        + v4.w * tanhff(bhi(pr.y) + q4.w);
                #pragma unroll
                for (int off = 32; off; off >>= 1) p += __shfl_down(p, off);
                if (ln == 0) sc[i] = p;
            }
        }
        __syncthreads();
        if (wv == 0) {
            float v0 = sc[ln], v1 = sc[ln + 64], v2 = sc[ln + 128];
            float v3 = (ln < 8) ? sc[ln + 192] : -1e30f;
            float mx = fmaxf(fmaxf(v0, v1), fmaxf(v2, v3));
            #pragma unroll
            for (int off = 32; off; off >>= 1) mx = fmaxf(mx, __shfl_xor(mx, off));
            float e0 = __expf(v0 - mx), e1 = __expf(v1 - mx), e2 = __expf(v2 - mx);
            float e3 = (ln < 8) ? __expf(v3 - mx) : 0.f;
            float ss = e0 + e1 + e2 + e3;
            #pragma unroll
            for (int off = 32; off; off >>= 1) ss += __shfl_xor(ss, off);
            const float inv = 1.0f / ss;
            float* ao = alout + (size_t)b * 40000 + (size_t)t * 200;
            al[ln]       = e0 * inv; ao[ln]       = e0 * inv;
            al[ln + 64]  = e1 * inv; ao[ln + 64]  = e1 * inv;
            al[ln + 128] = e2 * inv; ao[ln + 128] = e2 * inv;
            if (ln < 8) { al[ln + 192] = e3 * inv; ao[ln + 192] = e3 * inv; }
        }
        __syncthreads();
        // ---- context: att = align @ enc (enc streamed, al[i>=len]==0) ----
        {
            float a0 = 0.f, a1 = 0.f, a2 = 0.f, a3 = 0.f;
            for (int i = wv; i < len; i += 12) {
                const float w = al[i];
                const uint2 ev = *(const uint2*)(encG + i * 256 + ln * 4);
                a0 = fmaf(w, blo(ev.x), a0); a1 = fmaf(w, bhi(ev.x), a1);
                a2 = fmaf(w, blo(ev.y), a2); a3 = fmaf(w, bhi(ev.y), a3);
            }
            ((float4*)part)[wv * 64 + ln] = make_float4(a0, a1, a2, a3);
        }
        __syncthreads();
        if (tid < 256) {
            float s = 0.f;
            #pragma unroll
            for (int w2 = 0; w2 < 12; ++w2) s += part[w2][tid];
            const float s1 = __shfl_down(s, 1);
            if (!(tid & 1)) ((unsigned*)xcat)[64 + (tid >> 1)] = pkh(s, s1);  // att f16
        }
        __syncthreads();

        // ---- P3: d0 = [h_a' | att] @ pjW^T + pjb  (split-K by 2) ----
        // also: prefetch next step's x2 slice into xcat[0..15] (consumer is
        // P1 of t+1, >=3 barriers away; previous value consumed in P1 of t)
        if (tid >= 704 && tid < 720 && t + 1 < 200) {
            xcat[tid - 704] = X2h4[((size_t)(t + 1) * 256 + b) * 16 + (tid - 704)];
        }
        if (tid < 512) {
            const int half = tid >> 8, idx = tid & 255;
            const uint4* wp = pjWH + (size_t)half * 32 * 256 + idx;
            const uint4* src = half ? (const uint4*)(xcat + 16) : (const uint4*)ha_h;
            float s0 = 0.f, s1 = 0.f;
            #pragma unroll 8
            for (int k8 = 0; k8 < 32; k8 += 2) {
                s0 = dot8(wp[(size_t)k8 * 256], src[k8], s0);
                s1 = dot8(wp[(size_t)(k8 + 1) * 256], src[k8 + 1], s1);
            }
            part[half][idx] = s0 + s1;
        }
        __syncthreads();
        if (tid < 256) {
            const float d0 = part[0][tid] + part[1][tid] + pjb[tid];
            d0s[tid] = d0;
            const float dq = __shfl_down(d0, 1);
            if (!(tid & 1)) d0_h[tid >> 1] = pkh(d0, dq);
        }
        __syncthreads();

        // ---- P4: dec1 GRU; d1 = h1' + d0 ----
        {
            float ai0 = 0.f, ai1 = 0.f, ah0 = 0.f, ah1 = 0.f;
            const uint4* wp = w1ihH + tid;
            const uint4* xc = (const uint4*)d0_h;
            #pragma unroll 8
            for (int k8 = 0; k8 < 32; k8 += 2) {
                ai0 = dot8(wp[(size_t)k8 * 768], xc[k8], ai0);
                ai1 = dot8(wp[(size_t)(k8 + 1) * 768], xc[k8 + 1], ai1);
            }
            const uint4* wq = w1hhH + tid;
            const uint4* hc = (const uint4*)h1_h;
            #pragma unroll 8
            for (int k8 = 0; k8 < 32; k8 += 2) {
                ah0 = dot8(wq[(size_t)k8 * 768], hc[k8], ah0);
                ah1 = dot8(wq[(size_t)(k8 + 1) * 768], hc[k8 + 1], ah1);
            }
            gi[tid] = ai0 + ai1 + w1bih[tid];
            gh[tid] = ah0 + ah1 + w1bhh[tid];
        }
        __syncthreads();
        if (tid < 256) {
            const float r = sigf(gi[tid] + gh[tid]);
            const float z = sigf(gi[256 + tid] + gh[256 + tid]);
            const float n = tanhff(gi[512 + tid] + r * gh[512 + tid]);
            const float hp = (1.f - z) * n + z * h1s[tid];
            h1s[tid] = hp;
            const float d1 = hp + d0s[tid];
            d1s[tid] = d1;
            const float hq = __shfl_down(hp, 1);
            const float dq = __shfl_down(d1, 1);
            if (!(tid & 1)) { h1_h[tid >> 1] = pkh(hp, hq); d1_h[tid >> 1] = pkh(d1, dq); }
        }
        __syncthreads();

        // ---- P5: dec2 GRU; d2 = h2' + d1 -> dall[t] ----
        {
            float ai0 = 0.f, ai1 = 0.f, ah0 = 0.f, ah1 = 0.f;
            const uint4* wp = w2ihH + tid;
            const uint4* xc = (const uint4*)d1_h;
            #pragma unroll 8
            for (int k8 = 0; k8 < 32; k8 += 2) {
                ai0 = dot8(wp[(size_t)k8 * 768], xc[k8], ai0);
                ai1 = dot8(wp[(size_t)(k8 + 1) * 768], xc[k8 + 1], ai1);
            }
            const uint4* wq = w2hhH + tid;
            const uint4* hc = (const uint4*)h2_h;
            #pragma unroll 8
            for (int k8 = 0; k8 < 32; k8 += 2) {
                ah0 = dot8(wq[(size_t)k8 * 768], hc[k8], ah0);
                ah1 = dot8(wq[(size_t)(k8 + 1) * 768], hc[k8 + 1], ah1);
            }
            gi[tid] = ai0 + ai1 + w2bih[tid];
            gh[tid] = ah0 + ah1 + w2bhh[tid];
        }
        __syncthreads();
        if (tid < 256) {
            const float r = sigf(gi[tid] + gh[tid]);
            const float z = sigf(gi[256 + tid] + gh[256 + tid]);
            const float n = tanhff(gi[512 + tid] + r * gh[512 + tid]);
            const float hp = (1.f - z) * n + z * h2s[tid];
            h2s[tid] = hp;
            dall[((size_t)t * 256 + b) * 256 + tid] = hp + d1s[tid];
            const float hq = __shfl_down(hp, 1);
            if (!(tid & 1)) h2_h[tid >> 1] = pkh(hp, hq);
        }
        __syncthreads();
    }
}

// ---------------------------------------------------------------------------
extern "C" void kernel_launch(void* const* d_in, const int* in_sizes, int n_in,
                              void* d_out, int out_size, void* d_ws, size_t ws_size,
                              hipStream_t stream)
{
    const float* enc    = (const float*)d_in[0];
    const float* inputs = (const float*)d_in[1];
    const int*   mlen   = (const int*)d_in[2];
    const float* pW1 = (const float*)d_in[3];  const float* pb1 = (const float*)d_in[4];
    const float* pW2 = (const float*)d_in[5];  const float* pb2 = (const float*)d_in[6];
    const float* aWih = (const float*)d_in[7]; const float* abih = (const float*)d_in[8];
    const float* aWhh = (const float*)d_in[9]; const float* abhh = (const float*)d_in[10];
    const float* memW = (const float*)d_in[11];
    const float* qW   = (const float*)d_in[12];
    const float* vW   = (const float*)d_in[13];
    const float* pjW  = (const float*)d_in[14]; const float* pjb = (const float*)d_in[15];
    const float* w1ih = (const float*)d_in[16]; const float* w1bih = (const float*)d_in[17];
    const float* w1hh = (const float*)d_in[18]; const float* w1bhh = (const float*)d_in[19];
    const float* w2ih = (const float*)d_in[20]; const float* w2bih = (const float*)d_in[21];
    const float* w2hh = (const float*)d_in[22]; const float* w2bhh = (const float*)d_in[23];
    const float* melW = (const float*)d_in[24]; const float* melb = (const float*)d_in[25];

    float* out = (float*)d_out;
    float* ws  = (float*)d_ws;

    // workspace (float units)
    float* X1   = ws;                          // [51200,256] fp32 (aliased dall)
    float* dall = X1;                          // 13,107,200
    unsigned* X2h = (unsigned*)(ws + 13107200);          // 3,276,800 uints (f16 x2)
    unsigned short* pmH  = (unsigned short*)(ws + 16384000);  // bf16 pm
    unsigned short* encH = (unsigned short*)(ws + 22937600);  // bf16 enc
    uint4* aWihH = (uint4*)(ws + 29491200);    // 48*768
    uint4* aWhhH = aWihH + 36864;              // 32*768
    uint4* w1ihH = aWhhH + 24576;
    uint4* w1hhH = w1ihH + 24576;
    uint4* w2ihH = w1hhH + 24576;
    uint4* w2hhH = w2ihH + 24576;
    uint4* pjWH  = w2hhH + 24576;              // 64*256
    uint4* qWH   = pjWH + 16384;               // 32*256

    // pack weights to f16 [K/8][N]
    pack_wh<<<64, 256, 0, stream>>>(aWih, aWihH, 768, 384);
    pack_wh<<<64, 256, 0, stream>>>(aWhh, aWhhH, 768, 256);
    pack_wh<<<64, 256, 0, stream>>>(w1ih, w1ihH, 768, 256);
    pack_wh<<<64, 256, 0, stream>>>(w1hh, w1hhH, 768, 256);
    pack_wh<<<64, 256, 0, stream>>>(w2ih, w2ihH, 768, 256);
    pack_wh<<<64, 256, 0, stream>>>(w2hh, w2hhH, 768, 256);
    pack_wh<<<64, 256, 0, stream>>>(pjW,  pjWH,  256, 512);
    pack_wh<<<64, 256, 0, stream>>>(qW,   qWH,   256, 256);
    pack_bf16<<<1024, 256, 0, stream>>>(enc, encH, 13107200);

    // prenet1: X1 = relu(prev @ W1^T + b1)  fp32
    gemm128<2, 1><<<dim3(400, 2), 256, 0, stream>>>(
        inputs, 0, pW1, 400, pb1, X1, 256, 51200, 256, 400);
    // prenet2: X2 = relu(X1 @ W2^T + b2)  stored f16 (64 uints / row)
    gemm128<0, 4><<<dim3(400, 1), 256, 0, stream>>>(
        X1, 256, pW2, 256, pb2, (float*)X2h, 128, 51200, 128, 256);
    // processed_memory = enc @ memW^T  stored bf16
    gemm128<0, 3><<<dim3(400, 2), 256, 0, stream>>>(
        enc, 256, memW, 256, nullptr, (float*)pmH, 256, 51200, 256, 256);

    // zero-barrier persistent decoder: one batch row per block
    decoder_loop<<<256, 768, 0, stream>>>(
        (const uint4*)X2h, pmH, encH, mlen,
        aWihH, abih, aWhhH, abhh, qWH, vW, pjWH, pjb,
        w1ihH, w1bih, w1hhH, w1bhh, w2ihH, w2bih, w2hhH, w2bhh,
        dall, out + ALIGN_OFF);

    // mel projection: out[b,t,:] = dall[t,b,:] @ melW^T + melb
    gemm128<0, 2><<<dim3(400, 4), 256, 0, stream>>>(
        dall, 256, melW, 256, melb, out, 400, 51200, 400, 256);
}

// Round 15
// 8123.129 us; speedup vs baseline: 1.9333x; 1.9333x over previous
//
#include <hip/hip_runtime.h>
#include <math.h>

// B=256, T_ENC=200, D=256, T_MEL=1000, NMEL=80, R=5, IN_R=400, Td=200
#define ALIGN_OFF 20480000   // 256*200*400

typedef __fp16 h2_t __attribute__((ext_vector_type(2)));

__device__ __forceinline__ float sigf(float x) {
    return __builtin_amdgcn_rcpf(1.0f + __expf(-x));
}
__device__ __forceinline__ float tanhff(float x) {
    float e = __expf(2.0f * x);
    return 1.0f - 2.0f * __builtin_amdgcn_rcpf(e + 1.0f);
}
__device__ __forceinline__ unsigned short f2bf(float x) {
    unsigned u = __float_as_uint(x);
    return (unsigned short)((u + 0x7FFFu + ((u >> 16) & 1u)) >> 16);
}
__device__ __forceinline__ float blo(unsigned u) { return __uint_as_float(u << 16); }
__device__ __forceinline__ float bhi(unsigned u) { return __uint_as_float(u & 0xffff0000u); }
// pack two f32 -> f16x2 (RTZ)
__device__ __forceinline__ unsigned pkh(float a, float b) {
    h2_t r = __builtin_amdgcn_cvt_pkrtz(a, b);
    return __builtin_bit_cast(unsigned, r);
}
// f16 pair dot with f32 accumulate
__device__ __forceinline__ float dot2(unsigned w, unsigned a, float c) {
#if __has_builtin(__builtin_amdgcn_fdot2)
    return __builtin_amdgcn_fdot2(__builtin_bit_cast(h2_t, w),
                                  __builtin_bit_cast(h2_t, a), c, false);
#else
    h2_t wv = __builtin_bit_cast(h2_t, w), av = __builtin_bit_cast(h2_t, a);
    return c + (float)wv.x * (float)av.x + (float)wv.y * (float)av.y;
#endif
}
__device__ __forceinline__ float dot8(uint4 w, uint4 a, float c) {
    c = dot2(w.x, a.x, c); c = dot2(w.y, a.y, c);
    c = dot2(w.z, a.z, c); return dot2(w.w, a.w, c);
}

// ---------------------------------------------------------------------------
// 128x128-tile fp32 GEMM (prenet / processed_memory / mel).
// AMODE: 0 plain; 2 teacher-forcing virtual A (prenet1)
// EPI: 0 plain, 1 relu, 2 mel-layout store, 3 bf16 store (ld 256),
//      4 relu + f16 store (ld 128 halves = 64 uints)
// ---------------------------------------------------------------------------
template<int AMODE, int EPI>
__global__ __launch_bounds__(256)
void gemm128(const float* __restrict__ A, int lda,
             const float* __restrict__ W, int ldw,
             const float* __restrict__ bias,
             float* __restrict__ C, int ldc, int M, int N, int K)
{
    __shared__ float As[16][128];
    __shared__ float Bs[16][128];
    const int m0 = blockIdx.x * 128, n0 = blockIdx.y * 128;
    const int tid = threadIdx.x;
    const int tx = tid & 15, ty = tid >> 4;
    float acc[8][8] = {};
    for (int k0 = 0; k0 < K; k0 += 16) {
        {
            const int m = tid >> 1, h = (tid & 1) * 8;
            const int grow = m0 + m;
            float4 a0, a1;
            if (AMODE == 2) {
                int t = grow >> 8, b = grow & 255;
                if (t == 0) { a0 = make_float4(0, 0, 0, 0); a1 = a0; }
                else {
                    const float* p = A + (size_t)b * 80000 + (t - 1) * 400 + k0 + h;
                    a0 = *(const float4*)p; a1 = *(const float4*)(p + 4);
                }
            } else {
                const float* p = A + (size_t)grow * lda + k0 + h;
                a0 = *(const float4*)p; a1 = *(const float4*)(p + 4);
            }
            As[h + 0][m] = a0.x; As[h + 1][m] = a0.y; As[h + 2][m] = a0.z; As[h + 3][m] = a0.w;
            As[h + 4][m] = a1.x; As[h + 5][m] = a1.y; As[h + 6][m] = a1.z; As[h + 7][m] = a1.w;
            const int gn = n0 + m;
            float4 b0, b1;
            if (gn < N) {
                const float* p = W + (size_t)gn * ldw + k0 + h;
                b0 = *(const float4*)p; b1 = *(const float4*)(p + 4);
            } else { b0 = make_float4(0, 0, 0, 0); b1 = b0; }
            Bs[h + 0][m] = b0.x; Bs[h + 1][m] = b0.y; Bs[h + 2][m] = b0.z; Bs[h + 3][m] = b0.w;
            Bs[h + 4][m] = b1.x; Bs[h + 5][m] = b1.y; Bs[h + 6][m] = b1.z; Bs[h + 7][m] = b1.w;
        }
        __syncthreads();
        #pragma unroll
        for (int kk = 0; kk < 16; ++kk) {
            float av[8], bv[8];
            *(float4*)&av[0] = *(const float4*)&As[kk][ty * 8];
            *(float4*)&av[4] = *(const float4*)&As[kk][ty * 8 + 4];
            *(float4*)&bv[0] = *(const float4*)&Bs[kk][tx * 8];
            *(float4*)&bv[4] = *(const float4*)&Bs[kk][tx * 8 + 4];
            #pragma unroll
            for (int i = 0; i < 8; ++i)
                #pragma unroll
                for (int j = 0; j < 8; ++j)
                    acc[i][j] += av[i] * bv[j];
        }
        __syncthreads();
    }
    #pragma unroll
    for (int i = 0; i < 8; ++i) {
        const int row = m0 + ty * 8 + i;
        const int t_ = row >> 8, b_ = row & 255;
        #pragma unroll
        for (int j4 = 0; j4 < 2; ++j4) {
            const int col = n0 + tx * 8 + j4 * 4;
            if (col >= N) continue;
            float4 v;
            float* pv = &v.x;
            #pragma unroll
            for (int u = 0; u < 4; ++u) {
                float x = acc[i][j4 * 4 + u] + (bias ? bias[col + u] : 0.0f);
                if (EPI == 1 || EPI == 4) x = fmaxf(x, 0.0f);
                pv[u] = x;
            }
            if (EPI == 2)      *(float4*)(C + (size_t)b_ * 80000 + t_ * 400 + col) = v;
            else if (EPI == 3) {
                ushort4 o;
                o.x = f2bf(pv[0]); o.y = f2bf(pv[1]); o.z = f2bf(pv[2]); o.w = f2bf(pv[3]);
                *(ushort4*)((unsigned short*)C + (size_t)row * 256 + col) = o;
            } else if (EPI == 4) {
                uint2 o; o.x = pkh(pv[0], pv[1]); o.y = pkh(pv[2], pv[3]);
                *(uint2*)((unsigned*)C + (size_t)row * 64 + (col >> 1)) = o;
            } else *(float4*)(C + (size_t)row * ldc + col) = v;
        }
    }
}

// ---------------------------------------------------------------------------
// Pack W [N][K] f32 -> f16 [K/8][N] uint4 (8 halves per entry).
// ---------------------------------------------------------------------------
__global__ __launch_bounds__(256)
void pack_wh(const float* __restrict__ W, uint4* __restrict__ P, int N, int K)
{
    const int tot = N * (K >> 3);
    for (int i = blockIdx.x * 256 + threadIdx.x; i < tot; i += gridDim.x * 256) {
        const int n = i % N, k8 = i / N;
        const float* s = W + (size_t)n * K + (k8 << 3);
        uint4 o;
        o.x = pkh(s[0], s[1]); o.y = pkh(s[2], s[3]);
        o.z = pkh(s[4], s[5]); o.w = pkh(s[6], s[7]);
        P[(size_t)k8 * N + n] = o;
    }
}

// fp32 -> bf16 elementwise pack
__global__ __launch_bounds__(256)
void pack_bf16(const float* __restrict__ src, unsigned short* __restrict__ dst, int n)
{
    for (int i = (blockIdx.x * 256 + threadIdx.x) * 4; i < n; i += gridDim.x * 1024) {
        float4 v = *(const float4*)(src + i);
        ushort4 o;
        o.x = f2bf(v.x); o.y = f2bf(v.y); o.z = f2bf(v.z); o.w = f2bf(v.w);
        *(ushort4*)(dst + i) = o;
    }
}

// ---------------------------------------------------------------------------
// Zero-barrier persistent decoder (round-10 structure, verbatim): block b
// owns batch row b. pm row LDS-resident; state in LDS; f16 weights.
// ONE change vs round 10: enc context loads are NON-TEMPORAL (as u64, the
// form the builtin accepts) so the enc stream (3.2 MB/XCD/step) stops
// evicting the weight set (2.9 MB) from the XCD's 4 MB L2.
// ---------------------------------------------------------------------------
__global__ __launch_bounds__(768)
void decoder_loop(
    const uint4* __restrict__ X2h4,          // [200*256][16] uint4, f16 prenet out
    const unsigned short* __restrict__ pmH,  // [256][200][256] bf16
    const unsigned short* __restrict__ encH, // [256][200][256] bf16
    const int*   __restrict__ mlen,
    const uint4* __restrict__ aWihH, const float* __restrict__ abih,
    const uint4* __restrict__ aWhhH, const float* __restrict__ abhh,
    const uint4* __restrict__ qWH,   const float* __restrict__ vW,
    const uint4* __restrict__ pjWH,  const float* __restrict__ pjb,
    const uint4* __restrict__ w1ihH, const float* __restrict__ w1bih,
    const uint4* __restrict__ w1hhH, const float* __restrict__ w1bhh,
    const uint4* __restrict__ w2ihH, const float* __restrict__ w2bih,
    const uint4* __restrict__ w2hhH, const float* __restrict__ w2bhh,
    float* __restrict__ dall, float* __restrict__ alout)
{
    __shared__ unsigned short pmS[51200];    // this row's pm, bf16 (100 KB)
    __shared__ uint4 xcat[48];               // f16 [x2_t (16) | att (32)]
    __shared__ unsigned ha_h[128], h1_h[128], h2_h[128], d0_h[128], d1_h[128];
    __shared__ float hA[256], h1s[256], h2s[256], d0s[256], d1s[256];
    __shared__ float qv[256], vvS[256];
    __shared__ float sc[200], al[208];
    __shared__ float gi[768], gh[768];
    __shared__ float part[12][256];

    const int b = blockIdx.x, tid = threadIdx.x;
    const int wv = tid >> 6, ln = tid & 63;

    // one-time init: pm row -> LDS, states zero
    {
        const uint4* psrc = (const uint4*)(pmH + (size_t)b * 51200);
        for (int i = tid; i < 6400; i += 768) ((uint4*)pmS)[i] = psrc[i];
        if (tid < 256) { vvS[tid] = vW[tid]; hA[tid] = 0.f; h1s[tid] = 0.f; h2s[tid] = 0.f; }
        if (tid < 128) { ha_h[tid] = 0u; h1_h[tid] = 0u; h2_h[tid] = 0u; }
        if (tid < 32)  xcat[16 + tid] = make_uint4(0, 0, 0, 0);   // att = 0
    }
    const int len = mlen[b];
    const unsigned short* encG = encH + (size_t)b * 51200;
    __syncthreads();

    for (int t = 0; t < 200; ++t) {
        // ---- P1: attention GRU  h_a' = GRU([x2_t | att], h_a) ----
        if (tid < 16) xcat[tid] = X2h4[((size_t)t * 256 + b) * 16 + tid];
        __syncthreads();
        {
            float ai = 0.f, ah = 0.f;
            const uint4* wp = aWihH + tid;
            #pragma unroll 8
            for (int k8 = 0; k8 < 48; ++k8) {
                const uint4 w = wp[(size_t)k8 * 768], a = xcat[k8];
                ai = dot8(w, a, ai);
            }
            const uint4* wq = aWhhH + tid;
            const uint4* hc = (const uint4*)ha_h;
            #pragma unroll 8
            for (int k8 = 0; k8 < 32; ++k8) {
                const uint4 w = wq[(size_t)k8 * 768], a = hc[k8];
                ah = dot8(w, a, ah);
            }
            gi[tid] = ai + abih[tid];
            gh[tid] = ah + abhh[tid];
        }
        __syncthreads();
        if (tid < 256) {
            const float r = sigf(gi[tid] + gh[tid]);
            const float z = sigf(gi[256 + tid] + gh[256 + tid]);
            const float n = tanhff(gi[512 + tid] + r * gh[512 + tid]);
            const float hp = (1.f - z) * n + z * hA[tid];
            hA[tid] = hp;
            const float hq = __shfl_down(hp, 1);
            if (!(tid & 1)) ha_h[tid >> 1] = pkh(hp, hq);
        }
        __syncthreads();

        // ---- P2: q = h_a' @ qW^T ----
        if (tid < 256) {
            float s = 0.f;
            const uint4* qp = qWH + tid;
            const uint4* hc = (const uint4*)ha_h;
            #pragma unroll 8
            for (int k8 = 0; k8 < 32; ++k8) {
                const uint4 w = qp[(size_t)k8 * 256], a = hc[k8];
                s = dot8(w, a, s);
            }
            qv[tid] = s;
        }
        __syncthreads();
        // ---- scores from LDS pm: sc[i] = v . tanh(pm[i] + q), i < len ----
        {
            const float4 q4 = ((const float4*)qv)[ln];
            const float4 v4 = ((const float4*)vvS)[ln];
            for (int i = wv; i < 200; i += 12) {
                if (i < len) {
                    const uint2 pr = *(const uint2*)(pmS + i * 256 + ln * 4);
                    float p = v4.x * tanhff(blo(pr.x) + q4.x)
                            + v4.y * tanhff(bhi(pr.x) + q4.y)
                            + v4.z * tanhff(blo(pr.y) + q4.z)
                            + v4.w * tanhff(bhi(pr.y) + q4.w);
                    #pragma unroll
                    for (int off = 32; off; off >>= 1) p += __shfl_down(p, off);
                    if (ln == 0) sc[i] = p;
                } else if (ln == 0) sc[i] = -1e9f;
            }
        }
        __syncthreads();
        if (wv == 0) {
            float v0 = sc[ln], v1 = sc[ln + 64], v2 = sc[ln + 128];
            float v3 = (ln < 8) ? sc[ln + 192] : -1e30f;
            float mx = fmaxf(fmaxf(v0, v1), fmaxf(v2, v3));
            #pragma unroll
            for (int off = 32; off; off >>= 1) mx = fmaxf(mx, __shfl_xor(mx, off));
            float e0 = __expf(v0 - mx), e1 = __expf(v1 - mx), e2 = __expf(v2 - mx);
            float e3 = (ln < 8) ? __expf(v3 - mx) : 0.f;
            float ss = e0 + e1 + e2 + e3;
            #pragma unroll
            for (int off = 32; off; off >>= 1) ss += __shfl_xor(ss, off);
            const float inv = 1.0f / ss;
            float* ao = alout + (size_t)b * 40000 + (size_t)t * 200;
            al[ln]       = e0 * inv; ao[ln]       = e0 * inv;
            al[ln + 64]  = e1 * inv; ao[ln + 64]  = e1 * inv;
            al[ln + 128] = e2 * inv; ao[ln + 128] = e2 * inv;
            if (ln < 8) { al[ln + 192] = e3 * inv; ao[ln + 192] = e3 * inv; }
        }
        __syncthreads();
        // ---- context: att = align @ enc (enc NT-streamed, al[i>=len]==0) ----
        {
            float a0 = 0.f, a1 = 0.f, a2 = 0.f, a3 = 0.f;
            for (int i = wv; i < len; i += 12) {
                const float w = al[i];
                const unsigned long long ev = __builtin_nontemporal_load(
                    (const unsigned long long*)(encG + i * 256 + ln * 4));
                const unsigned elo = (unsigned)ev, ehi = (unsigned)(ev >> 32);
                a0 = fmaf(w, blo(elo), a0); a1 = fmaf(w, bhi(elo), a1);
                a2 = fmaf(w, blo(ehi), a2); a3 = fmaf(w, bhi(ehi), a3);
            }
            ((float4*)part)[wv * 64 + ln] = make_float4(a0, a1, a2, a3);
        }
        __syncthreads();
        if (tid < 256) {
            float s = 0.f;
            #pragma unroll
            for (int w2 = 0; w2 < 12; ++w2) s += part[w2][tid];
            const float s1 = __shfl_down(s, 1);
            if (!(tid & 1)) ((unsigned*)xcat)[64 + (tid >> 1)] = pkh(s, s1);  // att f16
        }
        __syncthreads();

        // ---- P3: d0 = [h_a' | att] @ pjW^T + pjb  (split-K by 2) ----
        if (tid < 512) {
            const int half = tid >> 8, idx = tid & 255;
            const uint4* wp = pjWH + (size_t)half * 32 * 256 + idx;
            const uint4* src = half ? (const uint4*)(xcat + 16) : (const uint4*)ha_h;
            float s = 0.f;
            #pragma unroll 8
            for (int k8 = 0; k8 < 32; ++k8) {
                const uint4 w = wp[(size_t)k8 * 256], a = src[k8];
                s = dot8(w, a, s);
            }
            part[half][idx] = s;
        }
        __syncthreads();
        if (tid < 256) {
            const float d0 = part[0][tid] + part[1][tid] + pjb[tid];
            d0s[tid] = d0;
            const float dq = __shfl_down(d0, 1);
            if (!(tid & 1)) d0_h[tid >> 1] = pkh(d0, dq);
        }
        __syncthreads();

        // ---- P4: dec1 GRU; d1 = h1' + d0 ----
        {
            float ai = 0.f, ah = 0.f;
            const uint4* wp = w1ihH + tid;
            const uint4* xc = (const uint4*)d0_h;
            #pragma unroll 8
            for (int k8 = 0; k8 < 32; ++k8) {
                const uint4 w = wp[(size_t)k8 * 768], a = xc[k8];
                ai = dot8(w, a, ai);
            }
            const uint4* wq = w1hhH + tid;
            const uint4* hc = (const uint4*)h1_h;
            #pragma unroll 8
            for (int k8 = 0; k8 < 32; ++k8) {
                const uint4 w = wq[(size_t)k8 * 768], a = hc[k8];
                ah = dot8(w, a, ah);
            }
            gi[tid] = ai + w1bih[tid];
            gh[tid] = ah + w1bhh[tid];
        }
        __syncthreads();
        if (tid < 256) {
            const float r = sigf(gi[tid] + gh[tid]);
            const float z = sigf(gi[256 + tid] + gh[256 + tid]);
            const float n = tanhff(gi[512 + tid] + r * gh[512 + tid]);
            const float hp = (1.f - z) * n + z * h1s[tid];
            h1s[tid] = hp;
            const float d1 = hp + d0s[tid];
            d1s[tid] = d1;
            const float hq = __shfl_down(hp, 1);
            const float dq = __shfl_down(d1, 1);
            if (!(tid & 1)) { h1_h[tid >> 1] = pkh(hp, hq); d1_h[tid >> 1] = pkh(d1, dq); }
        }
        __syncthreads();

        // ---- P5: dec2 GRU; d2 = h2' + d1 -> dall[t] ----
        {
            float ai = 0.f, ah = 0.f;
            const uint4* wp = w2ihH + tid;
            const uint4* xc = (const uint4*)d1_h;
            #pragma unroll 8
            for (int k8 = 0; k8 < 32; ++k8) {
                const uint4 w = wp[(size_t)k8 * 768], a = xc[k8];
                ai = dot8(w, a, ai);
            }
            const uint4* wq = w2hhH + tid;
            const uint4* hc = (const uint4*)h2_h;
            #pragma unroll 8
            for (int k8 = 0; k8 < 32; ++k8) {
                const uint4 w = wq[(size_t)k8 * 768], a = hc[k8];
                ah = dot8(w, a, ah);
            }
            gi[tid] = ai + w2bih[tid];
            gh[tid] = ah + w2bhh[tid];
        }
        __syncthreads();
        if (tid < 256) {
            const float r = sigf(gi[tid] + gh[tid]);
            const float z = sigf(gi[256 + tid] + gh[256 + tid]);
            const float n = tanhff(gi[512 + tid] + r * gh[512 + tid]);
            const float hp = (1.f - z) * n + z * h2s[tid];
            h2s[tid] = hp;
            dall[((size_t)t * 256 + b) * 256 + tid] = hp + d1s[tid];
            const float hq = __shfl_down(hp, 1);
            if (!(tid & 1)) h2_h[tid >> 1] = pkh(hp, hq);
        }
        __syncthreads();
    }
}

// ---------------------------------------------------------------------------
extern "C" void kernel_launch(void* const* d_in, const int* in_sizes, int n_in,
                              void* d_out, int out_size, void* d_ws, size_t ws_size,
                              hipStream_t stream)
{
    const float* enc    = (const float*)d_in[0];
    const float* inputs = (const float*)d_in[1];
    const int*   mlen   = (const int*)d_in[2];
    const float* pW1 = (const float*)d_in[3];  const float* pb1 = (const float*)d_in[4];
    const float* pW2 = (const float*)d_in[5];  const float* pb2 = (const float*)d_in[6];
    const float* aWih = (const float*)d_in[7]; const float* abih = (const float*)d_in[8];
    const float* aWhh = (const float*)d_in[9]; const float* abhh = (const float*)d_in[10];
    const float* memW = (const float*)d_in[11];
    const float* qW   = (const float*)d_in[12];
    const float* vW   = (const float*)d_in[13];
    const float* pjW  = (const float*)d_in[14]; const float* pjb = (const float*)d_in[15];
    const float* w1ih = (const float*)d_in[16]; const float* w1bih = (const float*)d_in[17];
    const float* w1hh = (const float*)d_in[18]; const float* w1bhh = (const float*)d_in[19];
    const float* w2ih = (const float*)d_in[20]; const float* w2bih = (const float*)d_in[21];
    const float* w2hh = (const float*)d_in[22]; const float* w2bhh = (const float*)d_in[23];
    const float* melW = (const float*)d_in[24]; const float* melb = (const float*)d_in[25];

    float* out = (float*)d_out;
    float* ws  = (float*)d_ws;

    // workspace (float units)
    float* X1   = ws;                          // [51200,256] fp32 (aliased dall)
    float* dall = X1;                          // 13,107,200
    unsigned* X2h = (unsigned*)(ws + 13107200);          // 3,276,800 uints (f16 x2)
    unsigned short* pmH  = (unsigned short*)(ws + 16384000);  // bf16 pm
    unsigned short* encH = (unsigned short*)(ws + 22937600);  // bf16 enc
    uint4* aWihH = (uint4*)(ws + 29491200);    // 48*768
    uint4* aWhhH = aWihH + 36864;              // 32*768
    uint4* w1ihH = aWhhH + 24576;
    uint4* w1hhH = w1ihH + 24576;
    uint4* w2ihH = w1hhH + 24576;
    uint4* w2hhH = w2ihH + 24576;
    uint4* pjWH  = w2hhH + 24576;              // 64*256
    uint4* qWH   = pjWH + 16384;               // 32*256

    // pack weights to f16 [K/8][N]
    pack_wh<<<64, 256, 0, stream>>>(aWih, aWihH, 768, 384);
    pack_wh<<<64, 256, 0, stream>>>(aWhh, aWhhH, 768, 256);
    pack_wh<<<64, 256, 0, stream>>>(w1ih, w1ihH, 768, 256);
    pack_wh<<<64, 256, 0, stream>>>(w1hh, w1hhH, 768, 256);
    pack_wh<<<64, 256, 0, stream>>>(w2ih, w2ihH, 768, 256);
    pack_wh<<<64, 256, 0, stream>>>(w2hh, w2hhH, 768, 256);
    pack_wh<<<64, 256, 0, stream>>>(pjW,  pjWH,  256, 512);
    pack_wh<<<64, 256, 0, stream>>>(qW,   qWH,   256, 256);
    pack_bf16<<<1024, 256, 0, stream>>>(enc, encH, 13107200);

    // prenet1: X1 = relu(prev @ W1^T + b1)  fp32
    gemm128<2, 1><<<dim3(400, 2), 256, 0, stream>>>(
        inputs, 0, pW1, 400, pb1, X1, 256, 51200, 256, 400);
    // prenet2: X2 = relu(X1 @ W2^T + b2)  stored f16 (64 uints / row)
    gemm128<0, 4><<<dim3(400, 1), 256, 0, stream>>>(
        X1, 256, pW2, 256, pb2, (float*)X2h, 128, 51200, 128, 256);
    // processed_memory = enc @ memW^T  stored bf16
    gemm128<0, 3><<<dim3(400, 2), 256, 0, stream>>>(
        enc, 256, memW, 256, nullptr, (float*)pmH, 256, 51200, 256, 256);

    // zero-barrier persistent decoder: one batch row per block
    decoder_loop<<<256, 768, 0, stream>>>(
        (const uint4*)X2h, pmH, encH, mlen,
        aWihH, abih, aWhhH, abhh, qWH, vW, pjWH, pjb,
        w1ihH, w1bih, w1hhH, w1bhh, w2ihH, w2bih, w2hhH, w2bhh,
        dall, out + ALIGN_OFF);

    // mel projection: out[b,t,:] = dall[t,b,:] @ melW^T + melb
    gemm128<0, 2><<<dim3(400, 4), 256, 0, stream>>>(
        dall, 256, melW, 256, melb, out, 400, 51200, 400, 256);
}